// Round 1
// baseline (567.970 us; speedup 1.0000x reference)
//
#include <hip/hip_runtime.h>

// Shapes (fixed per reference): B=2, L=2048, D=1024, H=16, Dh=64
typedef __bf16 bf16;
typedef __attribute__((ext_vector_type(8))) __bf16 bf16x8;
typedef __attribute__((ext_vector_type(4))) __bf16 bf16x4;
typedef __attribute__((ext_vector_type(4))) float f32x4;
typedef __attribute__((ext_vector_type(16))) float f32x16;

__device__ inline bf16 f2bf(float f) {
  unsigned u = __builtin_bit_cast(unsigned, f);
  u += 0x7fff + ((u >> 16) & 1);  // RNE
  unsigned short h = (unsigned short)(u >> 16);
  return __builtin_bit_cast(bf16, h);
}

// ---------------- fp32 -> bf16 conversion for x and the four W's ----------
__global__ __launch_bounds__(256) void cvt_kernel(
    const float* __restrict__ x, const float* __restrict__ wq,
    const float* __restrict__ wk, const float* __restrict__ wv,
    const float* __restrict__ wo, bf16* __restrict__ dst) {
  int idx = (blockIdx.x * 256 + threadIdx.x) * 4;
  const float* src;
  if (idx < 4194304) {
    src = x + idx;
  } else {
    int j = idx - 4194304;
    int w = j >> 20;  // uniform per block (1M boundaries align with blocks)
    const float* sw = (w == 0) ? wq : (w == 1) ? wk : (w == 2) ? wv : wo;
    src = sw + (j & 1048575);
  }
  float4 f = *(const float4*)src;
  bf16x4 o = {f2bf(f.x), f2bf(f.y), f2bf(f.z), f2bf(f.w)};
  *(bf16x4*)(dst + idx) = o;
}

// ---------------- QKV projection GEMM + RoPE epilogue ---------------------
// y[m=(b,l)][e] = sum_d x[m][d] * W[e][d], e in [0,3072)
// Each wave: one 32x32 C tile via mfma_f32_32x32x16_bf16, K-loop 64 iters.
// A-frag: m=lane&31, k=(lane>>5)*8+j (contig).  B-frag: n=lane&31 -> W row, contig k.
// C: col=lane&31, row=(reg&3)+8*(reg>>2)+4*(lane>>5)  [verified m74/m101]
__global__ __launch_bounds__(256) void gemm_qkv_kernel(
    const bf16* __restrict__ xb, const bf16* __restrict__ wb,
    const int* __restrict__ pos,
    bf16* __restrict__ Qb, bf16* __restrict__ Kb, bf16* __restrict__ Vtb) {
  int lane = threadIdx.x & 63;
  int w = threadIdx.x >> 6;
  int mb = blockIdx.y * 64 + (w >> 1) * 32;
  int nb = blockIdx.x * 64 + (w & 1) * 32;
  int l31 = lane & 31;
  int kofs = (lane >> 5) * 8;
  int e = nb + l31;
  const bf16* Ap = xb + (mb + l31) * 1024 + kofs;
  const bf16* Bp = wb + (e >> 10) * 1048576 + (e & 1023) * 1024 + kofs;
  f32x16 acc;
  for (int i = 0; i < 16; ++i) acc[i] = 0.f;
#pragma unroll 8
  for (int kt = 0; kt < 64; ++kt) {
    bf16x8 a = *(const bf16x8*)(Ap + kt * 16);
    bf16x8 b = *(const bf16x8*)(Bp + kt * 16);
    acc = __builtin_amdgcn_mfma_f32_32x32x16_bf16(a, b, acc, 0, 0, 0);
  }
  bool isv = (e >= 2048);
  int d = e & 63;
  int h = (e & 1023) >> 6;
  // inv_freq = theta^(-(d&~1)/64) = 2^(-(d&~1)*log2(10000)/64)
  float freq = exp2f(-(float)(d & ~1) * 0.20762051f);
  for (int r = 0; r < 16; ++r) {
    int row = (r & 3) + 8 * (r >> 2) + 4 * (lane >> 5);
    int m = mb + row;
    int b = m >> 11, ltok = m & 2047;
    float val = acc[r];
    float p = __shfl_xor(val, 1);  // pair partner (col e^1), all lanes execute
    float outv;
    if (!isv) {
      float angle = (float)pos[ltok] * freq;
      float sn, cs;
      sincosf(angle, &sn, &cs);
      outv = (e & 1) ? (p * sn + val * cs) : (val * cs - p * sn);
    } else {
      outv = val;
    }
    bf16 bv = f2bf(outv);
    if (e < 1024) {
      Qb[(((b << 4) + h) * 2048 + ltok) * 64 + d] = bv;       // (B,H,L,Dh)
    } else if (!isv) {
      Kb[(((b << 4) + h) * 2048 + ltok) * 64 + d] = bv;       // (B,H,L,Dh)
    } else {
      Vtb[(((b << 4) + h) * 64 + d) * 2048 + ltok] = bv;      // (B,H,Dh,L) transposed
    }
  }
}

// ---------------- causal flash attention ----------------------------------
// S^T = K*Q^T (C: col=lane&15 -> q, row=quad*4+reg -> key): softmax state is
// per-lane scalar. P^T goes through LDS to become the PV B-operand.
// O^T = Vt*P^T accumulated in fp32; normalize and store (B,L,H*Dh) bf16.
__global__ __launch_bounds__(256) void attn_kernel(
    const bf16* __restrict__ Qb, const bf16* __restrict__ Kb,
    const bf16* __restrict__ Vtb, bf16* __restrict__ Ob) {
  __shared__ __align__(16) bf16 pbuf[4][16 * 40];  // stride 40: aligned b128, 2-way-free banks
  int lane = threadIdx.x & 63;
  int w = threadIdx.x >> 6;
  int q16 = lane & 15;
  int quad = lane >> 4;
  int bh = blockIdx.y;
  int qb = blockIdx.x * 64;
  const bf16* Qp = Qb + (size_t)bh * 131072;
  const bf16* Kp = Kb + (size_t)bh * 131072;
  const bf16* Vp = Vtb + (size_t)bh * 131072;
  int qrow = qb + w * 16 + q16;
  bf16x8 qf0 = *(const bf16x8*)(Qp + qrow * 64 + quad * 8);
  bf16x8 qf1 = *(const bf16x8*)(Qp + qrow * 64 + 32 + quad * 8);
  f32x4 ot0, ot1, ot2, ot3;
  for (int i = 0; i < 4; ++i) { ot0[i] = 0.f; ot1[i] = 0.f; ot2[i] = 0.f; ot3[i] = 0.f; }
  float mrun = -__builtin_inff(), lrun = 0.f;
  int ntiles = (qb >> 5) + 2;  // block-uniform causal bound (max q = qb+63)
  for (int t = 0; t < ntiles; ++t) {
    int kb = t * 32;
    const bf16* kr0 = Kp + (kb + q16) * 64;
    const bf16* kr1 = kr0 + 16 * 64;
    bf16x8 ka00 = *(const bf16x8*)(kr0 + quad * 8);
    bf16x8 ka01 = *(const bf16x8*)(kr0 + 32 + quad * 8);
    bf16x8 ka10 = *(const bf16x8*)(kr1 + quad * 8);
    bf16x8 ka11 = *(const bf16x8*)(kr1 + 32 + quad * 8);
    f32x4 s0, s1;
    for (int i = 0; i < 4; ++i) { s0[i] = 0.f; s1[i] = 0.f; }
    s0 = __builtin_amdgcn_mfma_f32_16x16x32_bf16(ka00, qf0, s0, 0, 0, 0);
    s0 = __builtin_amdgcn_mfma_f32_16x16x32_bf16(ka01, qf1, s0, 0, 0, 0);
    s1 = __builtin_amdgcn_mfma_f32_16x16x32_bf16(ka10, qf0, s1, 0, 0, 0);
    s1 = __builtin_amdgcn_mfma_f32_16x16x32_bf16(ka11, qf1, s1, 0, 0, 0);
    float sv[8];
    int kb0 = kb + quad * 4;
    for (int r = 0; r < 4; ++r) {
      int key0 = kb0 + r;
      int key1 = kb0 + 16 + r;
      sv[r]     = (key0 <= qrow) ? s0[r] * 0.125f : -__builtin_inff();
      sv[4 + r] = (key1 <= qrow) ? s1[r] * 0.125f : -__builtin_inff();
    }
    float tmax = sv[0];
    for (int i = 1; i < 8; ++i) tmax = fmaxf(tmax, sv[i]);
    tmax = fmaxf(tmax, __shfl_xor(tmax, 16));
    tmax = fmaxf(tmax, __shfl_xor(tmax, 32));
    float nm = fmaxf(mrun, tmax);      // finite from t=0 on (key 0 never masked)
    float al = expf(mrun - nm);
    mrun = nm;
    float ps = 0.f;
    for (int i = 0; i < 8; ++i) { sv[i] = expf(sv[i] - nm); ps += sv[i]; }
    ps += __shfl_xor(ps, 16);
    ps += __shfl_xor(ps, 32);
    lrun = lrun * al + ps;
    ot0 *= al; ot1 *= al; ot2 *= al; ot3 *= al;
    bf16x4 w0 = {f2bf(sv[0]), f2bf(sv[1]), f2bf(sv[2]), f2bf(sv[3])};
    bf16x4 w1 = {f2bf(sv[4]), f2bf(sv[5]), f2bf(sv[6]), f2bf(sv[7])};
    *(bf16x4*)&pbuf[w][q16 * 40 + quad * 4] = w0;        // keys quad*4..+3
    *(bf16x4*)&pbuf[w][q16 * 40 + 16 + quad * 4] = w1;   // keys 16+quad*4..+3
    __syncthreads();
    bf16x8 pb = *(const bf16x8*)&pbuf[w][q16 * 40 + quad * 8];  // B-frag: keys quad*8..+7
    const bf16* vbase = Vp + q16 * 2048 + kb + quad * 8;
    ot0 = __builtin_amdgcn_mfma_f32_16x16x32_bf16(*(const bf16x8*)(vbase), pb, ot0, 0, 0, 0);
    ot1 = __builtin_amdgcn_mfma_f32_16x16x32_bf16(*(const bf16x8*)(vbase + 16 * 2048), pb, ot1, 0, 0, 0);
    ot2 = __builtin_amdgcn_mfma_f32_16x16x32_bf16(*(const bf16x8*)(vbase + 32 * 2048), pb, ot2, 0, 0, 0);
    ot3 = __builtin_amdgcn_mfma_f32_16x16x32_bf16(*(const bf16x8*)(vbase + 48 * 2048), pb, ot3, 0, 0, 0);
    __syncthreads();
  }
  float inv = 1.f / lrun;
  int b = bh >> 4, h = bh & 15;
  bf16* obase = Ob + ((size_t)(b * 2048 + qrow)) * 1024 + h * 64;
  for (int r = 0; r < 4; ++r) {
    int dq = quad * 4 + r;
    obase[dq]      = f2bf(ot0[r] * inv);
    obase[16 + dq] = f2bf(ot1[r] * inv);
    obase[32 + dq] = f2bf(ot2[r] * inv);
    obase[48 + dq] = f2bf(ot3[r] * inv);
  }
}

// ---------------- output projection GEMM (fp32 out) -----------------------
__global__ __launch_bounds__(256) void gemm_out_kernel(
    const bf16* __restrict__ Ob, const bf16* __restrict__ wob,
    float* __restrict__ out) {
  int lane = threadIdx.x & 63;
  int w = threadIdx.x >> 6;
  int mb = blockIdx.y * 64 + (w >> 1) * 32;
  int nb = blockIdx.x * 64 + (w & 1) * 32;
  int l31 = lane & 31;
  int kofs = (lane >> 5) * 8;
  const bf16* Ap = Ob + (mb + l31) * 1024 + kofs;
  const bf16* Bp = wob + (nb + l31) * 1024 + kofs;
  f32x16 acc;
  for (int i = 0; i < 16; ++i) acc[i] = 0.f;
#pragma unroll 8
  for (int kt = 0; kt < 64; ++kt) {
    bf16x8 a = *(const bf16x8*)(Ap + kt * 16);
    bf16x8 b = *(const bf16x8*)(Bp + kt * 16);
    acc = __builtin_amdgcn_mfma_f32_32x32x16_bf16(a, b, acc, 0, 0, 0);
  }
  int e = nb + l31;
  for (int r = 0; r < 16; ++r) {
    int row = (r & 3) + 8 * (r >> 2) + 4 * (lane >> 5);
    out[(size_t)(mb + row) * 1024 + e] = acc[r];
  }
}

extern "C" void kernel_launch(void* const* d_in, const int* in_sizes, int n_in,
                              void* d_out, int out_size, void* d_ws, size_t ws_size,
                              hipStream_t stream) {
  const float* x  = (const float*)d_in[0];
  const float* wq = (const float*)d_in[1];
  const float* wk = (const float*)d_in[2];
  const float* wv = (const float*)d_in[3];
  const float* wo = (const float*)d_in[4];
  const int* pos  = (const int*)d_in[5];
  float* out = (float*)d_out;
  // workspace layout (bf16 elements): xb[4M] | wb[4x1M] | Q[4M] | K[4M] | Vt[4M] | O[4M]
  bf16* wsb = (bf16*)d_ws;
  bf16* xb  = wsb;
  bf16* wb  = wsb + 4194304;
  bf16* Qb  = wsb + 8388608;
  bf16* Kb  = wsb + 12582912;
  bf16* Vtb = wsb + 16777216;
  bf16* Obf = wsb + 20971520;
  hipLaunchKernelGGL(cvt_kernel, dim3(8192), dim3(256), 0, stream, x, wq, wk, wv, wo, wsb);
  hipLaunchKernelGGL(gemm_qkv_kernel, dim3(48, 64), dim3(256), 0, stream, xb, wb, pos, Qb, Kb, Vtb);
  hipLaunchKernelGGL(attn_kernel, dim3(32, 32), dim3(256), 0, stream, Qb, Kb, Vtb, Obf);
  hipLaunchKernelGGL(gemm_out_kernel, dim3(16, 64), dim3(256), 0, stream, Obf, wb + 3 * 1048576, out);
}

// Round 2
// 270.581 us; speedup vs baseline: 2.0991x; 2.0991x over previous
//
#include <hip/hip_runtime.h>

// Shapes (fixed per reference): B=2, L=2048, D=1024, H=16, Dh=64
typedef __bf16 bf16;
typedef __attribute__((ext_vector_type(8))) __bf16 bf16x8;
typedef __attribute__((ext_vector_type(4))) __bf16 bf16x4;
typedef __attribute__((ext_vector_type(4))) float f32x4;

__device__ inline bf16 f2bf(float f) {
  unsigned u = __builtin_bit_cast(unsigned, f);
  u += 0x7fff + ((u >> 16) & 1);  // RNE
  unsigned short h = (unsigned short)(u >> 16);
  return __builtin_bit_cast(bf16, h);
}

__device__ inline void gl_lds16(const bf16* g, bf16* l) {
  __builtin_amdgcn_global_load_lds(
      (const __attribute__((address_space(1))) void*)g,
      (__attribute__((address_space(3))) void*)l, 16, 0, 0);
}

// ---------------- fp32 -> bf16 conversion for x and the four W's ----------
__global__ __launch_bounds__(256) void cvt_kernel(
    const float* __restrict__ x, const float* __restrict__ wq,
    const float* __restrict__ wk, const float* __restrict__ wv,
    const float* __restrict__ wo, bf16* __restrict__ dst) {
  int idx = (blockIdx.x * 256 + threadIdx.x) * 4;
  const float* src;
  if (idx < 4194304) {
    src = x + idx;
  } else {
    int j = idx - 4194304;
    int w = j >> 20;  // uniform per block
    const float* sw = (w == 0) ? wq : (w == 1) ? wk : (w == 2) ? wv : wo;
    src = sw + (j & 1048575);
  }
  float4 f = *(const float4*)src;
  bf16x4 o = {f2bf(f.x), f2bf(f.y), f2bf(f.z), f2bf(f.w)};
  *(bf16x4*)(dst + idx) = o;
}

// ---------------- QKV projection GEMM (m97-style) + RoPE epilogue ---------
// 128x128 tile, BK=32, global_load_lds staging, 4 waves x (64x64 quadrant).
__global__ __launch_bounds__(256) void gemm_qkv_kernel(
    const bf16* __restrict__ xb, const bf16* __restrict__ wb,
    const int* __restrict__ pos,
    bf16* __restrict__ Qb, bf16* __restrict__ Kb, bf16* __restrict__ Vtb) {
  __shared__ __align__(16) bf16 As[128 * 32];
  __shared__ __align__(16) bf16 Bs[128 * 32];
  int tid = threadIdx.x;
  int lane = tid & 63, w = tid >> 6;
  int l15 = lane & 15, quad = lane >> 4;
  int mb = blockIdx.y * 128, nb = blockIdx.x * 128;
  int mq = (w & 1) * 64, nq = (w >> 1) * 64;
  // staging: wave w covers rows [w*32, w*32+32) of both tiles
  const bf16* agp = xb + (size_t)(mb + w * 32 + (lane >> 2)) * 1024 + (lane & 3) * 8;
  const bf16* bgp = wb + (size_t)(nb + w * 32 + (lane >> 2)) * 1024 + (lane & 3) * 8;
  bf16* alp = As + (w * 32) * 32;
  bf16* blp = Bs + (w * 32) * 32;
  f32x4 acc[4][4];
#pragma unroll
  for (int i = 0; i < 4; ++i)
#pragma unroll
    for (int j = 0; j < 4; ++j)
      for (int r = 0; r < 4; ++r) acc[i][j][r] = 0.f;
  for (int kt = 0; kt < 32; ++kt) {
    gl_lds16(agp, alp);
    gl_lds16(agp + 16 * 1024, alp + 16 * 32);
    gl_lds16(bgp, blp);
    gl_lds16(bgp + 16 * 1024, blp + 16 * 32);
    agp += 32; bgp += 32;
    __syncthreads();
    bf16x8 af[4], bf[4];
#pragma unroll
    for (int mt = 0; mt < 4; ++mt)
      af[mt] = *(const bf16x8*)(As + (mq + mt * 16 + l15) * 32 + quad * 8);
#pragma unroll
    for (int nt = 0; nt < 4; ++nt)
      bf[nt] = *(const bf16x8*)(Bs + (nq + nt * 16 + l15) * 32 + quad * 8);
#pragma unroll
    for (int mt = 0; mt < 4; ++mt)
#pragma unroll
      for (int nt = 0; nt < 4; ++nt)
        acc[mt][nt] = __builtin_amdgcn_mfma_f32_16x16x32_bf16(af[mt], bf[nt], acc[mt][nt], 0, 0, 0);
    __syncthreads();
  }
  // epilogue: C[m][n]: n(col)=l15, m(row)=quad*4+reg. RoPE pairs via shfl_xor(1).
#pragma unroll
  for (int nt = 0; nt < 4; ++nt) {
    int e = nb + nq + nt * 16 + l15;  // 0..3071
    bool isv = (e >= 2048);
    int d = e & 63;
    int h = (e & 1023) >> 6;
    float freq = exp2f(-(float)(d & ~1) * 0.20762051f);
#pragma unroll
    for (int mt = 0; mt < 4; ++mt) {
#pragma unroll
      for (int r = 0; r < 4; ++r) {
        int m = mb + mq + mt * 16 + quad * 4 + r;
        int b = m >> 11, ltok = m & 2047;
        float val = acc[mt][nt][r];
        float p = __shfl_xor(val, 1);
        float outv;
        if (!isv) {
          float angle = (float)pos[ltok] * freq;
          float sn, cs;
          sincosf(angle, &sn, &cs);
          outv = (e & 1) ? (p * sn + val * cs) : (val * cs - p * sn);
        } else {
          outv = val;
        }
        bf16 bv = f2bf(outv);
        if (e < 1024) {
          Qb[(((b << 4) + h) * 2048 + ltok) * 64 + d] = bv;
        } else if (!isv) {
          Kb[(((b << 4) + h) * 2048 + ltok) * 64 + d] = bv;
        } else {
          Vtb[(((b << 4) + h) * 64 + d) * 2048 + ltok] = bv;
        }
      }
    }
  }
}

// ---------------- causal flash attention v2 --------------------------------
// One wave per block. Wave: 32 q rows x 64 keys/iter. S^T = K*Q^T,
// O^T = Vt*P^T. P^T through per-wave LDS (row stride 72 bf16).
#define SCALE_L2E 0.18033688f  // 0.125 * log2(e)
__global__ __launch_bounds__(64) void attn_kernel(
    const bf16* __restrict__ Qb, const bf16* __restrict__ Kb,
    const bf16* __restrict__ Vtb, bf16* __restrict__ Ob) {
  __shared__ __align__(16) bf16 pbuf[2][16 * 72];
  int lane = threadIdx.x;
  int l15 = lane & 15, quad = lane >> 4;
  int bidx = blockIdx.x;
  int bh = bidx & 31;
  int qt = 63 - (bidx >> 5);  // longest blocks dispatch first (LPT)
  int qbase = qt * 32;
  const bf16* Qp = Qb + (size_t)bh * 131072;
  const bf16* Kp = Kb + (size_t)bh * 131072;
  const bf16* Vp = Vtb + (size_t)bh * 131072;
  bf16x8 qf[2][2];
#pragma unroll
  for (int j = 0; j < 2; ++j)
#pragma unroll
    for (int c = 0; c < 2; ++c)
      qf[j][c] = *(const bf16x8*)(Qp + (qbase + j * 16 + l15) * 64 + c * 32 + quad * 8);
  f32x4 oacc[2][4];
#pragma unroll
  for (int j = 0; j < 2; ++j)
#pragma unroll
    for (int dt = 0; dt < 4; ++dt)
      for (int r = 0; r < 4; ++r) oacc[j][dt][r] = 0.f;
  float mrun[2] = {-__builtin_inff(), -__builtin_inff()};
  float lrun[2] = {0.f, 0.f};
  int nfull = qt >> 1;
  for (int t = 0; t <= nfull; ++t) {
    int kb = t * 64;
    bool masked = (t == nfull);  // wave-uniform
    bf16x8 kf[4][2], vf[4][2];
#pragma unroll
    for (int kt = 0; kt < 4; ++kt) {
      kf[kt][0] = *(const bf16x8*)(Kp + (kb + kt * 16 + l15) * 64 + quad * 8);
      kf[kt][1] = *(const bf16x8*)(Kp + (kb + kt * 16 + l15) * 64 + 32 + quad * 8);
    }
#pragma unroll
    for (int dt = 0; dt < 4; ++dt) {
      vf[dt][0] = *(const bf16x8*)(Vp + (dt * 16 + l15) * 2048 + kb + quad * 8);
      vf[dt][1] = *(const bf16x8*)(Vp + (dt * 16 + l15) * 2048 + kb + 32 + quad * 8);
    }
#pragma unroll
    for (int j = 0; j < 2; ++j) {
      f32x4 s[4];
#pragma unroll
      for (int kt = 0; kt < 4; ++kt) {
        for (int r = 0; r < 4; ++r) s[kt][r] = 0.f;
        s[kt] = __builtin_amdgcn_mfma_f32_16x16x32_bf16(kf[kt][0], qf[j][0], s[kt], 0, 0, 0);
        s[kt] = __builtin_amdgcn_mfma_f32_16x16x32_bf16(kf[kt][1], qf[j][1], s[kt], 0, 0, 0);
      }
      float sv[16];
      int q = qbase + j * 16 + l15;
      if (masked) {
#pragma unroll
        for (int kt = 0; kt < 4; ++kt)
#pragma unroll
          for (int r = 0; r < 4; ++r) {
            int key = kb + kt * 16 + quad * 4 + r;
            sv[kt * 4 + r] = (key <= q) ? s[kt][r] * SCALE_L2E : -__builtin_inff();
          }
      } else {
#pragma unroll
        for (int kt = 0; kt < 4; ++kt)
#pragma unroll
          for (int r = 0; r < 4; ++r) sv[kt * 4 + r] = s[kt][r] * SCALE_L2E;
      }
      float tm = sv[0];
#pragma unroll
      for (int i = 1; i < 16; ++i) tm = fmaxf(tm, sv[i]);
      tm = fmaxf(tm, __shfl_xor(tm, 16));
      tm = fmaxf(tm, __shfl_xor(tm, 32));
      float nm = fmaxf(mrun[j], tm);
      float al = exp2f(mrun[j] - nm);
      mrun[j] = nm;
      float ps = 0.f;
#pragma unroll
      for (int i = 0; i < 16; ++i) { sv[i] = exp2f(sv[i] - nm); ps += sv[i]; }
      ps += __shfl_xor(ps, 16);
      ps += __shfl_xor(ps, 32);
      lrun[j] = lrun[j] * al + ps;
#pragma unroll
      for (int dt = 0; dt < 4; ++dt) oacc[j][dt] *= al;
#pragma unroll
      for (int kt = 0; kt < 4; ++kt) {
        bf16x4 pw = {f2bf(sv[kt * 4]), f2bf(sv[kt * 4 + 1]), f2bf(sv[kt * 4 + 2]), f2bf(sv[kt * 4 + 3])};
        *(bf16x4*)&pbuf[j][l15 * 72 + kt * 16 + quad * 4] = pw;
      }
    }
    __syncthreads();
#pragma unroll
    for (int j = 0; j < 2; ++j) {
      bf16x8 pb0 = *(const bf16x8*)&pbuf[j][l15 * 72 + quad * 8];
      bf16x8 pb1 = *(const bf16x8*)&pbuf[j][l15 * 72 + 32 + quad * 8];
#pragma unroll
      for (int dt = 0; dt < 4; ++dt) {
        oacc[j][dt] = __builtin_amdgcn_mfma_f32_16x16x32_bf16(vf[dt][0], pb0, oacc[j][dt], 0, 0, 0);
        oacc[j][dt] = __builtin_amdgcn_mfma_f32_16x16x32_bf16(vf[dt][1], pb1, oacc[j][dt], 0, 0, 0);
      }
    }
    __syncthreads();
  }
  int b = bh >> 4, h = bh & 15;
#pragma unroll
  for (int j = 0; j < 2; ++j) {
    float inv = 1.f / lrun[j];
    int q = qbase + j * 16 + l15;
    bf16* obase = Ob + ((size_t)(b * 2048 + q)) * 1024 + h * 64;
#pragma unroll
    for (int dt = 0; dt < 4; ++dt)
#pragma unroll
      for (int r = 0; r < 4; ++r)
        obase[dt * 16 + quad * 4 + r] = f2bf(oacc[j][dt][r] * inv);
  }
}

// ---------------- output projection GEMM (128x64 tile, fp32 out) -----------
__global__ __launch_bounds__(256) void gemm_out_kernel(
    const bf16* __restrict__ Ob, const bf16* __restrict__ wob,
    float* __restrict__ out) {
  __shared__ __align__(16) bf16 As[128 * 32];
  __shared__ __align__(16) bf16 Bs[64 * 32];
  int tid = threadIdx.x;
  int lane = tid & 63, w = tid >> 6;
  int l15 = lane & 15, quad = lane >> 4;
  int mb = blockIdx.y * 128, nb = blockIdx.x * 64;
  int mq = (w & 1) * 64, nq = (w >> 1) * 32;
  const bf16* agp = Ob + (size_t)(mb + w * 32 + (lane >> 2)) * 1024 + (lane & 3) * 8;
  const bf16* bgp = wob + (size_t)(nb + w * 16 + (lane >> 2)) * 1024 + (lane & 3) * 8;
  bf16* alp = As + (w * 32) * 32;
  bf16* blp = Bs + (w * 16) * 32;
  f32x4 acc[4][2];
#pragma unroll
  for (int i = 0; i < 4; ++i)
#pragma unroll
    for (int j = 0; j < 2; ++j)
      for (int r = 0; r < 4; ++r) acc[i][j][r] = 0.f;
  for (int kt = 0; kt < 32; ++kt) {
    gl_lds16(agp, alp);
    gl_lds16(agp + 16 * 1024, alp + 16 * 32);
    gl_lds16(bgp, blp);
    agp += 32; bgp += 32;
    __syncthreads();
    bf16x8 af[4], bf[2];
#pragma unroll
    for (int mt = 0; mt < 4; ++mt)
      af[mt] = *(const bf16x8*)(As + (mq + mt * 16 + l15) * 32 + quad * 8);
#pragma unroll
    for (int nt = 0; nt < 2; ++nt)
      bf[nt] = *(const bf16x8*)(Bs + (nq + nt * 16 + l15) * 32 + quad * 8);
#pragma unroll
    for (int mt = 0; mt < 4; ++mt)
#pragma unroll
      for (int nt = 0; nt < 2; ++nt)
        acc[mt][nt] = __builtin_amdgcn_mfma_f32_16x16x32_bf16(af[mt], bf[nt], acc[mt][nt], 0, 0, 0);
    __syncthreads();
  }
#pragma unroll
  for (int mt = 0; mt < 4; ++mt)
#pragma unroll
    for (int nt = 0; nt < 2; ++nt)
#pragma unroll
      for (int r = 0; r < 4; ++r)
        out[(size_t)(mb + mq + mt * 16 + quad * 4 + r) * 1024 + nb + nq + nt * 16 + l15] = acc[mt][nt][r];
}

extern "C" void kernel_launch(void* const* d_in, const int* in_sizes, int n_in,
                              void* d_out, int out_size, void* d_ws, size_t ws_size,
                              hipStream_t stream) {
  const float* x  = (const float*)d_in[0];
  const float* wq = (const float*)d_in[1];
  const float* wk = (const float*)d_in[2];
  const float* wv = (const float*)d_in[3];
  const float* wo = (const float*)d_in[4];
  const int* pos  = (const int*)d_in[5];
  float* out = (float*)d_out;
  // ws layout (bf16 elems): xb[4M] | wb[4x1M] | Q[4M] | K[4M] | Vt[4M] | O[4M]
  bf16* wsb = (bf16*)d_ws;
  bf16* xb  = wsb;
  bf16* wb  = wsb + 4194304;
  bf16* Qb  = wsb + 8388608;
  bf16* Kb  = wsb + 12582912;
  bf16* Vtb = wsb + 16777216;
  bf16* Obf = wsb + 20971520;
  hipLaunchKernelGGL(cvt_kernel, dim3(8192), dim3(256), 0, stream, x, wq, wk, wv, wo, wsb);
  hipLaunchKernelGGL(gemm_qkv_kernel, dim3(24, 32), dim3(256), 0, stream, xb, wb, pos, Qb, Kb, Vtb);
  hipLaunchKernelGGL(attn_kernel, dim3(2048), dim3(64), 0, stream, Qb, Kb, Vtb, Obf);
  hipLaunchKernelGGL(gemm_out_kernel, dim3(16, 32), dim3(256), 0, stream, Obf, wb + 3 * 1048576, out);
}